// Round 5
// baseline (254.551 us; speedup 1.0000x reference)
//
#include <hip/hip_runtime.h>
#include <hip/hip_bf16.h>

#define BB 8
#define SS 4096
#define DD 1024
#define LL 16

typedef __attribute__((ext_vector_type(8))) short short8;
typedef __attribute__((ext_vector_type(4))) float fl4;

static __device__ __forceinline__ short f2bf(float f) {
    // round-to-nearest-even fp32 -> bf16 (inputs finite, no NaN path needed)
    unsigned u = __float_as_uint(f);
    u += 0x7FFFu + ((u >> 16) & 1u);
    return (short)(u >> 16);
}

// Setup: summ -> bf16; zero Z and out (atomic targets).
__global__ __launch_bounds__(256) void k_prep(const float* __restrict__ summ,
                                              short* __restrict__ summb,
                                              float* __restrict__ Z,
                                              float* __restrict__ out) {
    int i = blockIdx.x * 256 + threadIdx.x;   // 64 blocks -> 16384 threads
    if (i < LL * DD) summb[i] = f2bf(summ[i]);
    if (i < BB * LL) Z[i] = 0.f;
    if (i < BB * DD) out[i] = 0.f;
}

// Pass 1: e[b][s][l] = exp(score), Z[b][l] += partials.
// K-SPLIT: two waves per 16(l)x16(s) tile, each doing K=512 (halves of D),
// partial MFMA accs combined via LDS. 2 tiles/block, 1024 blocks ->
// 4 blocks/CU, 16 waves/CU (2x R3's occupancy). Prefetch-by-1, full unroll.
// D layout: col(s)=lane&15, row(l)=(lane>>4)*4+reg  [m89-verified]
__global__ __launch_bounds__(256, 4) void k_scores(const float* __restrict__ mem,
                                                   const short* __restrict__ summb,
                                                   float* __restrict__ e,
                                                   float* __restrict__ Z) {
    __shared__ float red[2][64 * 4];
    int widx = threadIdx.x >> 6;
    int tp   = widx >> 1;              // tile slot within block (0/1)
    int h    = widx & 1;               // k-half
    int tile = blockIdx.x * 2 + tp;    // 0..2047
    int lane = threadIdx.x & 63;
    int b  = tile >> 8;                // 256 tiles per batch
    int s0 = (tile & 255) << 4;
    int o  = lane & 15;                // s within tile
    int qd = lane >> 4;
    int kb = h << 9;                   // 0 or 512

    const short* arow = summb + o * DD + kb + qd * 8;
    const float* mrow = mem + ((size_t)b * SS + s0 + o) * DD + kb + qd * 8;

    fl4 acc = {0.f, 0.f, 0.f, 0.f};
    fl4 p0 = *(const fl4*)(mrow);
    fl4 p1 = *(const fl4*)(mrow + 4);
    #pragma unroll
    for (int i = 0; i < 16; ++i) {     // 16 x (K=32) = 512
        fl4 n0, n1;
        if (i < 15) {
            n0 = *(const fl4*)(mrow + (i + 1) * 32);
            n1 = *(const fl4*)(mrow + (i + 1) * 32 + 4);
        }
        short8 a = *(const short8*)(arow + i * 32);
        short8 bb;
        bb[0] = f2bf(p0[0]); bb[1] = f2bf(p0[1]);
        bb[2] = f2bf(p0[2]); bb[3] = f2bf(p0[3]);
        bb[4] = f2bf(p1[0]); bb[5] = f2bf(p1[1]);
        bb[6] = f2bf(p1[2]); bb[7] = f2bf(p1[3]);
        acc = __builtin_amdgcn_mfma_f32_16x16x32_bf16(a, bb, acc, 0, 0, 0);
        p0 = n0; p1 = n1;
    }

    if (h == 1) *(fl4*)&red[tp][lane * 4] = acc;
    __syncthreads();
    if (h == 0) {
        fl4 other = *(const fl4*)&red[tp][lane * 4];
        acc += other;

        const float scale = 0.03125f;  // 1/sqrt(1024)
        fl4 ev;
        #pragma unroll
        for (int r = 0; r < 4; ++r) ev[r] = __expf(acc[r] * scale);
        // e[b][s][l]: s = s0+o, l = qd*4+r (consecutive -> one fl4 store)
        *(fl4*)&e[((size_t)b * SS + s0 + o) * LL + qd * 4] = ev;

        // Z partial: sum over 16 s (o) per qd group; xor 1,2,4,8 stay in-group
        fl4 zs = ev;
        #pragma unroll
        for (int r = 0; r < 4; ++r) {
            float v = zs[r];
            v += __shfl_xor(v, 1, 64);
            v += __shfl_xor(v, 2, 64);
            v += __shfl_xor(v, 4, 64);
            v += __shfl_xor(v, 8, 64);
            zs[r] = v;
        }
        if (o == 0) {                  // lanes 0,16,32,48: l = qd*4+r
            #pragma unroll
            for (int r = 0; r < 4; ++r) atomicAdd(&Z[b * LL + qd * 4 + r], zs[r]);
        }
    }
}

// Pass 2: coef[l]=w[l]/Z[b][l]; q[s]=sum_l coef*e[b][s][l];
//         out[b][d] += sum_{s in 32-chunk} q[s]*mem[b][s][d]  (L3-fed re-read)
__global__ __launch_bounds__(256, 4) void k_ctx(const float* __restrict__ mem,
                                                const float* __restrict__ e,
                                                const float* __restrict__ Z,
                                                const float* __restrict__ w,
                                                float* __restrict__ out) {
    int blk = blockIdx.x;            // 1024 = 8 b x 128 chunks of 32 s
    int b  = blk >> 7;
    int s0 = (blk & 127) << 5;
    int t = threadIdx.x;

    __shared__ float coef[LL];
    __shared__ float qs[32];
    if (t < LL) coef[t] = w[t] / Z[b * LL + t];
    // coef written and read by wave 0 only -> in-wave visibility, no barrier
    if (t < 32) {
        const float* ep = e + ((size_t)b * SS + s0 + t) * LL;  // 64 B/thread
        float qv = 0.f;
        #pragma unroll
        for (int l = 0; l < LL; ++l) qv += coef[l] * ep[l];
        qs[t] = qv;
    }
    __syncthreads();

    const float* mb = mem + ((size_t)b * SS + s0) * DD + t * 4;
    fl4 acc = {0.f, 0.f, 0.f, 0.f};
    fl4 c = *(const fl4*)(mb);
    #pragma unroll
    for (int i = 0; i < 32; ++i) {
        fl4 n;
        if (i < 31) n = *(const fl4*)(mb + (size_t)(i + 1) * DD);
        acc += qs[i] * c;
        c = n;
    }
    float* op = out + (size_t)b * DD + t * 4;
    atomicAdd(op + 0, acc[0]);
    atomicAdd(op + 1, acc[1]);
    atomicAdd(op + 2, acc[2]);
    atomicAdd(op + 3, acc[3]);
}

extern "C" void kernel_launch(void* const* d_in, const int* in_sizes, int n_in,
                              void* d_out, int out_size, void* d_ws, size_t ws_size,
                              hipStream_t stream) {
    const float* mem  = (const float*)d_in[0];  // [8,4096,1024] fp32
    const float* summ = (const float*)d_in[1];  // [16,1024] fp32
    const float* w    = (const float*)d_in[2];  // [1,16] fp32
    float* out = (float*)d_out;                 // [8,1024] fp32

    char* ws = (char*)d_ws;
    short* summb = (short*)ws;                                   // 32 KB (pad to 64)
    float* Z     = (float*)(ws + 64 * 1024);                     // 512 B (pad to 4K)
    float* e     = (float*)(ws + 68 * 1024);                     // 2 MB [b][s][l]

    k_prep<<<64, 256, 0, stream>>>(summ, summb, Z, out);
    k_scores<<<1024, 256, 0, stream>>>(mem, summb, e, Z);
    k_ctx<<<1024, 256, 0, stream>>>(mem, e, Z, w, out);
}